// Round 2
// baseline (2425.131 us; speedup 1.0000x reference)
//
#include <hip/hip_runtime.h>

#define NN 100000
#define NE 1600000
#define DD 64
#define HID 128

typedef const __attribute__((address_space(1))) unsigned int* gas1_t;
typedef __attribute__((address_space(3)))       unsigned int* las3_t;

// ---------------------------------------------------------------------------
// Edge kernel, dst-blocked multipass.
//   Per wave: scan a contiguous 261-edge strip, bucket edges by dst>>13
//   (13 buckets x 8192 nodes = 2MB agg slice, fits every per-XCD L2),
//   then process buckets in order. All 1536 blocks are co-resident (6/CU),
//   so the whole GPU works one agg slice at a time -> atomics are L2-hit
//   RMWs instead of L2-thrash round trips (Round-0 WRITE_SIZE=400MB == full
//   atomic volume was the smoking gun).
//   lin_w lives in LDS, XOR-swizzled so lane j's row-j ds_read_b128 is
//   bank-minimal (no 64-VGPR pin -> no spill, VGPR stays low).
// ---------------------------------------------------------------------------
#define EGRID 1536
#define SPW   261            // 6144 waves * 261 >= NE
#define ARENA 264
#define NBKT  13             // dst >> 13; 99999>>13 == 12

__global__ __launch_bounds__(256, 6)
void edge_kernel(const float* __restrict__ edge_attr,
                 const int*   __restrict__ edge_index,
                 const float* __restrict__ x,
                 const float* __restrict__ lin_w,
                 const float* __restrict__ lin_b,
                 float* __restrict__ agg)
{
    __shared__ float Wsw[DD * DD];                     // 16 KB swizzled lin_w
    __shared__ unsigned long long arena[4][ARENA];     // 8.25 KB packed tuples
    __shared__ int cnt[4][16], off[4][16], cur[4][16];

    const int tid  = threadIdx.x;
    const int lane = tid & 63;
    const int wv   = tid >> 6;

    // Swizzled weight stage: Wsw[j*64 + (k ^ ((j&15)<<2))] = lin_w[j][k].
    for (int i = tid; i < DD * DD; i += 256) {
        const int j = i >> 6, k = i & 63;
        Wsw[(j << 6) | (k ^ ((j & 15) << 2))] = lin_w[i];
    }
    if (lane < 16) cnt[wv][lane] = 0;
    __syncthreads();                                   // only barrier; uniform

    const int wid = __builtin_amdgcn_readfirstlane(blockIdx.x * 4 + wv);
    const int s   = wid * SPW;
    const int e   = (s + SPW < NE) ? (s + SPW) : NE;
    const float bj = lin_b[lane];
    const int   sw = (lane & 15) << 2;

    if (s < NE) {
        // Phase A: bucket histogram (coalesced dst reads).
        for (int i = s + lane; i < e; i += 64)
            atomicAdd(&cnt[wv][edge_index[NE + i] >> 13], 1);
        // Phase B: per-wave exclusive prefix.
        if (lane == 0) {
            int a = 0;
            for (int b = 0; b < NBKT; ++b) {
                off[wv][b] = a; cur[wv][b] = a; a += cnt[wv][b];
            }
        }
        // Phase C: scatter packed (eid<<40 | dst<<20 | src).
        for (int i = s + lane; i < e; i += 64) {
            const int dst = edge_index[NE + i];
            const int src = edge_index[i];
            const int slot = atomicAdd(&cur[wv][dst >> 13], 1);
            arena[wv][slot] = ((unsigned long long)i << 40) |
                              ((unsigned long long)dst << 20) |
                              (unsigned long long)src;
        }

        // Passes: whole GPU sweeps agg slice by slice.
        for (int p = 0; p < NBKT; ++p) {
            const int n = cnt[wv][p];
            const int o = off[wv][p];
            for (int i = 0; i < n; ++i) {
                const unsigned long long t = arena[wv][o + i]; // uniform b64
                const int src = (int)(t & 0xFFFFF);
                const int dst = (int)((t >> 20) & 0xFFFFF);
                const int eg  = (int)(t >> 40);

                const float xv = x[(size_t)src * DD + lane];   // coalesced
                const float4* ev =
                    reinterpret_cast<const float4*>(edge_attr + (size_t)eg * DD);

                float a0 = 0.f, a1 = 0.f, a2 = 0.f, a3 = 0.f;
                #pragma unroll
                for (int q = 0; q < 16; ++q) {
                    const float4 e4 = ev[q];                   // same-addr bcast
                    const float4 w4 = *reinterpret_cast<const float4*>(
                        &Wsw[(lane << 6) | ((4 * q) ^ sw)]);   // swizzled b128
                    a0 = fmaf(e4.x, w4.x, a0);
                    a1 = fmaf(e4.y, w4.y, a1);
                    a2 = fmaf(e4.z, w4.z, a2);
                    a3 = fmaf(e4.w, w4.w, a3);
                }
                float m = xv + bj + ((a0 + a1) + (a2 + a3));
                m = m > 0.0f ? m : 0.0f;
                unsafeAtomicAdd(&agg[(size_t)dst * DD + lane], m);
            }
        }
    }
}

// ---------------------------------------------------------------------------
// Node MLP: block = 4 waves, tile = 64 nodes (16/wave, two 8-node groups).
// All weights in LDS (swizzled rows, b128 reads); h / h1 via uniform
// ds_read_b128 broadcasts. wls buffer is reused: W0sw (layer1) then W1sw
// (layer2) with barriers. No per-lane weight arrays -> no spill.
// ---------------------------------------------------------------------------
#define MT 64

__global__ __launch_bounds__(256, 2)
void mlp_kernel(const float* __restrict__ h_in,
                float* __restrict__ out,
                const float* __restrict__ w0, const float* __restrict__ b0,
                const float* __restrict__ w1, const float* __restrict__ b1)
{
    __shared__ float hls[MT * DD];        // 16 KB staged h tile
    __shared__ float h1s[MT * HID];       // 32 KB hidden activations
    __shared__ float wls[HID * DD];       // 32 KB W0sw, then W1sw

    const int tid  = threadIdx.x;
    const int lane = tid & 63;
    const int wvu  = __builtin_amdgcn_readfirstlane(tid >> 6);
    const int nbse = blockIdx.x * MT;
    const int sw   = (lane & 15) << 2;

    // Stage h tile (guarded for the partial last tile).
    #pragma unroll
    for (int c = 0; c < 4; ++c) {
        const int o = c * 1024 + wvu * 256;
        if ((size_t)nbse * DD + o + lane * 4 < (size_t)NN * DD)
            __builtin_amdgcn_global_load_lds(
                (gas1_t)(h_in + (size_t)nbse * DD + o + lane * 4),
                (las3_t)(&hls[o]), 16, 0, 0);
    }
    // Stage W0 swizzled: wls[j*64 + (k ^ ((j&15)<<2))] = w0[j][k], j<128.
    for (int i = tid; i < HID * DD; i += 256) {
        const int j = i >> 6, k = i & 63;
        wls[(j << 6) | (k ^ ((j & 15) << 2))] = w0[i];
    }
    __syncthreads();

    const float b0a = b0[lane], b0b = b0[lane + 64], b1j = b1[lane];
    const float* wrA = &wls[lane << 6];
    const float* wrB = &wls[(lane + 64) << 6];

    // ---- layer 1: lane computes h1 rows `lane` and `lane+64`, 8 nodes/pass
    #pragma unroll
    for (int g = 0; g < 2; ++g) {
        float accA[8], accB[8];
        #pragma unroll
        for (int n = 0; n < 8; ++n) { accA[n] = b0a; accB[n] = b0b; }
        const int n0 = wvu * 16 + g * 8;
        for (int k4 = 0; k4 < DD / 4; ++k4) {
            const float4 wa = *reinterpret_cast<const float4*>(&wrA[(4 * k4) ^ sw]);
            const float4 wb = *reinterpret_cast<const float4*>(&wrB[(4 * k4) ^ sw]);
            #pragma unroll
            for (int n = 0; n < 8; ++n) {
                const float4 h4 = *reinterpret_cast<const float4*>(
                    &hls[(n0 + n) * DD + 4 * k4]);            // uniform bcast
                accA[n] = fmaf(h4.x, wa.x, accA[n]);
                accA[n] = fmaf(h4.y, wa.y, accA[n]);
                accA[n] = fmaf(h4.z, wa.z, accA[n]);
                accA[n] = fmaf(h4.w, wa.w, accA[n]);
                accB[n] = fmaf(h4.x, wb.x, accB[n]);
                accB[n] = fmaf(h4.y, wb.y, accB[n]);
                accB[n] = fmaf(h4.z, wb.z, accB[n]);
                accB[n] = fmaf(h4.w, wb.w, accB[n]);
            }
        }
        #pragma unroll
        for (int n = 0; n < 8; ++n) {
            const float vA = accA[n], vB = accB[n];
            h1s[(n0 + n) * HID + lane]      = vA > 0.0f ? vA : 0.0f;
            h1s[(n0 + n) * HID + 64 + lane] = vB > 0.0f ? vB : 0.0f;
        }
    }
    __syncthreads();
    // Stage W1 swizzled into the same buffer: row j has 128 entries.
    for (int i = tid; i < DD * HID; i += 256) {
        const int j = i >> 7, k = i & 127;
        wls[(j << 7) | (k ^ ((j & 15) << 2))] = w1[i];
    }
    __syncthreads();

    // ---- layer 2: lane computes output col `lane`, 8 nodes/pass
    const float* wr1 = &wls[lane << 7];
    #pragma unroll
    for (int g = 0; g < 2; ++g) {
        float acc[8];
        #pragma unroll
        for (int n = 0; n < 8; ++n) acc[n] = b1j;
        const int n0 = wvu * 16 + g * 8;
        for (int k4 = 0; k4 < HID / 4; ++k4) {
            const float4 w4 = *reinterpret_cast<const float4*>(&wr1[(4 * k4) ^ sw]);
            #pragma unroll
            for (int n = 0; n < 8; ++n) {
                const float4 p4 = *reinterpret_cast<const float4*>(
                    &h1s[(n0 + n) * HID + 4 * k4]);           // uniform bcast
                acc[n] = fmaf(p4.x, w4.x, acc[n]);
                acc[n] = fmaf(p4.y, w4.y, acc[n]);
                acc[n] = fmaf(p4.z, w4.z, acc[n]);
                acc[n] = fmaf(p4.w, w4.w, acc[n]);
            }
        }
        #pragma unroll
        for (int n = 0; n < 8; ++n) {
            const int gn = nbse + n0 + n;
            if (gn < NN) out[(size_t)gn * DD + lane] = acc[n];
        }
    }
}

extern "C" void kernel_launch(void* const* d_in, const int* in_sizes, int n_in,
                              void* d_out, int out_size, void* d_ws, size_t ws_size,
                              hipStream_t stream) {
    const float* x          = (const float*)d_in[0];
    const int*   edge_index = (const int*)  d_in[1];
    const float* edge_attr  = (const float*)d_in[2];
    const float* lin_w      = (const float*)d_in[3];
    const float* lin_b      = (const float*)d_in[4];
    const float* w0         = (const float*)d_in[5];
    const float* b0         = (const float*)d_in[6];
    const float* w1         = (const float*)d_in[7];
    const float* b1         = (const float*)d_in[8];
    float* out = (float*)d_out;

    const size_t hbytes = (size_t)NN * DD * sizeof(float);
    float* hbuf = (ws_size >= hbytes) ? (float*)d_ws : out;

    // h starts as x (EPS=0: h = (1+eps)*x + agg).
    hipMemcpyAsync(hbuf, x, hbytes, hipMemcpyDeviceToDevice, stream);

    edge_kernel<<<EGRID, 256, 0, stream>>>(edge_attr, edge_index, x,
                                           lin_w, lin_b, hbuf);
    mlp_kernel<<<(NN + MT - 1) / MT, 256, 0, stream>>>(hbuf, out, w0, b0, w1, b1);
}